// Round 14
// baseline (144.412 us; speedup 1.0000x reference)
//
#include <hip/hip_runtime.h>
#include <math.h>

typedef __attribute__((ext_vector_type(8)))  short short8;    // 8 bf16 = 4 VGPRs
typedef __attribute__((ext_vector_type(4)))  float floatx4;   // 16x16 MFMA C/D
typedef __attribute__((ext_vector_type(16))) float floatx16;  // 32x32 MFMA C/D

#define MFMA16(a, b, c) __builtin_amdgcn_mfma_f32_16x16x32_bf16(a, b, c, 0, 0, 0)
#define MFMA32(a, b, c) __builtin_amdgcn_mfma_f32_32x32x16_bf16(a, b, c, 0, 0, 0)

constexpr int NSEQ = 2048;
constexpr int DIN  = 768;
constexpr int NH   = 12;
constexpr float QSCALE = 0.18033688011112042f;  // log2(e)/8

constexpr int PK = 72;   // Ks pitch: 144 B rows, 16 B-aligned
constexpr int PV = 136;  // Vt pitch: 128 keys + 8 pad, 272 B rows, 16 B-aligned

__device__ __forceinline__ ushort f2bf(float f) {   // RNE fp32 -> bf16
    unsigned u = __float_as_uint(f);
    u += 0x7FFF + ((u >> 16) & 1);
    return (ushort)(u >> 16);
}
__device__ __forceinline__ float bf2f(ushort u) {
    return __uint_as_float(((unsigned)u) << 16);
}
__device__ __forceinline__ unsigned cvt_pk_bf16(float lo, float hi) {
    unsigned r;
    asm("v_cvt_pk_bf16_f32 %0, %1, %2" : "=v"(r) : "v"(lo), "v"(hi));
    return r;
}
__device__ __forceinline__ short8 pk8(float4 a, float4 b) {
    union { unsigned u[4]; short8 s; } r;
    r.u[0] = cvt_pk_bf16(a.x, a.y);
    r.u[1] = cvt_pk_bf16(a.z, a.w);
    r.u[2] = cvt_pk_bf16(b.x, b.y);
    r.u[3] = cvt_pk_bf16(b.z, b.w);
    return r.s;
}
// LDS-only barrier: orders ds ops across the block WITHOUT draining vmcnt.
__device__ __forceinline__ void bar_lds() {
    asm volatile("s_waitcnt lgkmcnt(0)" ::: "memory");
    __builtin_amdgcn_s_barrier();
}

// -----------------------------------------------------------------------------
// Kernel 1: h = x @ Wq^T, fused f32->bf16, DOUBLE-BUFFERED LDS (r10 verified).
// BM=64 x BN=64, grid (64,12) = 768 blocks, 3/CU. UNCHANGED.
// -----------------------------------------------------------------------------
__global__ __launch_bounds__(256, 3)
void qkv_mfma(const float* __restrict__ x, const float* __restrict__ Wq,
              ushort* __restrict__ h)
{
    __shared__ ushort As[2][64 * PK];
    __shared__ ushort Bs[2][64 * PK];

    const int tid  = threadIdx.x;
    const int w    = tid >> 6;
    const int lane = tid & 63;
    const int m    = lane & 15;
    const int quad = lane >> 4;
    const int r0   = blockIdx.x * 64;
    const int c0   = blockIdx.y * 64;
    const int mrow0 = (w & 1) * 32;
    const int ncol0 = (w >> 1) * 32;

    const int srow = tid >> 3;
    const int scol = (tid & 7) * 8;

    floatx4 C[2][2] = {};
    float4 arf[2][2], brf[2][2];

    #pragma unroll
    for (int i = 0; i < 2; ++i) {
        const float* ax = x  + (size_t)(r0 + srow + i * 32) * DIN + scol;
        const float* bx = Wq + (size_t)(c0 + srow + i * 32) * DIN + scol;
        arf[i][0] = ((const float4*)ax)[0]; arf[i][1] = ((const float4*)ax)[1];
        brf[i][0] = ((const float4*)bx)[0]; brf[i][1] = ((const float4*)bx)[1];
    }
    #pragma unroll
    for (int i = 0; i < 2; ++i) {
        *(short8*)&As[0][(srow + i * 32) * PK + scol] = pk8(arf[i][0], arf[i][1]);
        *(short8*)&Bs[0][(srow + i * 32) * PK + scol] = pk8(brf[i][0], brf[i][1]);
    }
    #pragma unroll
    for (int i = 0; i < 2; ++i) {
        const float* ax = x  + (size_t)(r0 + srow + i * 32) * DIN + 64 + scol;
        const float* bx = Wq + (size_t)(c0 + srow + i * 32) * DIN + 64 + scol;
        arf[i][0] = ((const float4*)ax)[0]; arf[i][1] = ((const float4*)ax)[1];
        brf[i][0] = ((const float4*)bx)[0]; brf[i][1] = ((const float4*)bx)[1];
    }
    bar_lds();

    for (int kk = 0; kk < 12; ++kk) {
        const int cur = kk & 1;

        #pragma unroll
        for (int kt2 = 0; kt2 < 2; ++kt2) {
            short8 a0 = *(const short8*)&As[cur][(mrow0 + m)      * PK + kt2 * 32 + quad * 8];
            short8 a1 = *(const short8*)&As[cur][(mrow0 + 16 + m) * PK + kt2 * 32 + quad * 8];
            short8 b0 = *(const short8*)&Bs[cur][(ncol0 + m)      * PK + kt2 * 32 + quad * 8];
            short8 b1 = *(const short8*)&Bs[cur][(ncol0 + 16 + m) * PK + kt2 * 32 + quad * 8];
            C[0][0] = MFMA16(a0, b0, C[0][0]);
            C[0][1] = MFMA16(a0, b1, C[0][1]);
            C[1][0] = MFMA16(a1, b0, C[1][0]);
            C[1][1] = MFMA16(a1, b1, C[1][1]);
        }

        if (kk + 1 < 12) {
            const int nxt = cur ^ 1;
            #pragma unroll
            for (int i = 0; i < 2; ++i) {
                *(short8*)&As[nxt][(srow + i * 32) * PK + scol] = pk8(arf[i][0], arf[i][1]);
                *(short8*)&Bs[nxt][(srow + i * 32) * PK + scol] = pk8(brf[i][0], brf[i][1]);
            }
            if (kk + 2 < 12) {
                const int k0 = (kk + 2) * 64;
                #pragma unroll
                for (int i = 0; i < 2; ++i) {
                    const float* ax = x  + (size_t)(r0 + srow + i * 32) * DIN + k0 + scol;
                    const float* bx = Wq + (size_t)(c0 + srow + i * 32) * DIN + k0 + scol;
                    arf[i][0] = ((const float4*)ax)[0]; arf[i][1] = ((const float4*)ax)[1];
                    brf[i][0] = ((const float4*)bx)[0]; brf[i][1] = ((const float4*)bx)[1];
                }
            }
            bar_lds();
        }
    }

    #pragma unroll
    for (int mt = 0; mt < 2; ++mt)
        #pragma unroll
        for (int nt = 0; nt < 2; ++nt) {
            int cg = c0 + ncol0 + nt * 16 + m;
            int head = cg >> 6, d = cg & 63;
            #pragma unroll
            for (int r = 0; r < 4; ++r) {
                int rg = r0 + mrow0 + mt * 16 + quad * 4 + r;
                int b = rg >> 11, q = rg & 2047;
                h[((size_t)(b * NH + head) * NSEQ + q) * 64 + d] = f2bf(C[mt][nt][r]);
            }
        }
}

// -----------------------------------------------------------------------------
// Kernel 2: causal flash attention — 128-KEY TILES (iteration-latency test).
// Invariant across r1..r13: ~99 block-iters/CU x ~1100 cyc = the 45 us wall,
// at any occupancy / LDS-op count. This halves iters: 32 q x 128 keys per
// block-iter; pair-blocks (qt, 63-qt) give EXACTLY 17 iters/block for every p
// (ceil((qt+1)/4) + ceil((64-qt)/4) = 17). Grid (32,24) = 768 = 3/CU -> 51
// block-iters/CU. 2 waves = key-halves (64 keys each). In-register P via
// cvt_pk + permlane32_swap (r13-verified, byte-identical math). Swizzles use
// the CORRECT bits this time: column-block += 2*(row>>3) breaks the pitch-72
// mod-8 row aliasing (bank-audited: every access at wave64 minimum).
// -----------------------------------------------------------------------------
__global__ __launch_bounds__(128, 3)
void attn_mfma(const ushort* __restrict__ h, float* __restrict__ out)
{
    __shared__ ushort Ks[128 * PK];     // [key][d]   18432 B, swizzled blocks
    __shared__ ushort Vt[64 * PV];      // [d][key]   17408 B, swizzled blocks

    const int tid  = threadIdx.x;
    const int w    = tid >> 6;          // key-half 0/1 (64 keys)
    const int lane = tid & 63;
    const int col  = lane & 31;         // q index (and fragment row)
    const int hi   = lane >> 5;

    const int p  = blockIdx.x;          // pair id 0..31
    const int bh = blockIdx.y;          // 0..23
    const ushort* __restrict__ Hh = h + (size_t)bh * NSEQ * 64;

    // staging: thread covers 4 key rows (kr4..kr4+3) x 2 d-blocks (dbb,dbb+1)
    const int kr4 = (tid & 31) * 4;
    const int dbb = (tid >> 5) * 2;     // 0,2,4,6
    const int rg4 = (kr4 >> 3) & 3;     // row-group term for Ks swizzle
    const int csw0 = ((dbb     + 2 * rg4) & 7) * 8;
    const int csw1 = ((dbb + 1 + 2 * rg4) & 7) * 8;
    const int kb   = kr4 >> 3;          // Vt key-block 0..15
    const int koff = kr4 & 7;           // 0 or 4
    const int kbp0 = ((kb + 2 * ((dbb)     & 3)) & 15) * 8 + koff;
    const int kbp1 = ((kb + 2 * ((dbb + 1) & 3)) & 15) * 8 + koff;

    const int swadd = 2 * (col >> 3);   // read-side swizzle addend

    float* Om = (float*)&Ks[0];         // merge scratch [64][33] f32 (8448 B)
    float* Lg = (float*)&Vt[0];         // wave1's l [32]

    short8 fr[4][2];                    // prefetch: 4 rows x 2 d-blocks
#define PRE(KT) do {                                                           \
    _Pragma("unroll")                                                          \
    for (int j = 0; j < 4; ++j) {                                              \
        const ushort* s_ = Hh + ((size_t)(KT) * 128 + kr4 + j) * 64 + dbb * 8; \
        fr[j][0] = *(const short8*)s_;                                         \
        fr[j][1] = *(const short8*)(s_ + 8);                                   \
    }                                                                          \
} while (0)

    #pragma unroll 1
    for (int half = 0; half < 2; ++half) {
        if (half) bar_lds();            // scratch reads done before restaging

        const int qt  = half ? p : (63 - p);
        const int q0  = qt * 32;
        const int nkt = (qt + 4) >> 2;  // # of 128-key tiles (pair-sum = 17)

        // Q fragments: B-operand, lane col = q, k = s*16 + hi*8 + j
        short8 qa[4];
        #pragma unroll
        for (int s = 0; s < 4; ++s) {
            short8 raw = *(const short8*)(Hh + (size_t)(q0 + col) * 64 + s * 16 + hi * 8);
            #pragma unroll
            for (int j = 0; j < 8; ++j)
                qa[s][j] = (short)f2bf(bf2f((ushort)raw[j]) * QSCALE);
        }

        floatx16 O[2] = {};             // O^T: d = dt*32 + dl(reg,hi), q = col
        float lacc = 0.0f;

        PRE(0);

        for (int kt = 0; kt < nkt; ++kt) {
            bar_lds();                  // prev iter's ka/va reads complete

            // ---- stage: Ks 8 x b128 (swizzled) + Vt 16 x b64 (4-key packs)
            #pragma unroll
            for (int j = 0; j < 4; ++j) {
                *(short8*)&Ks[(kr4 + j) * PK + csw0] = fr[j][0];
                *(short8*)&Ks[(kr4 + j) * PK + csw1] = fr[j][1];
            }
            {
                union { short8 v; ushort u[8]; } f[4][2];
                #pragma unroll
                for (int j = 0; j < 4; ++j) { f[j][0].v = fr[j][0]; f[j][1].v = fr[j][1]; }
                #pragma unroll
                for (int b = 0; b < 2; ++b) {
                    const int kcol = b ? kbp1 : kbp0;
                    #pragma unroll
                    for (int i = 0; i < 8; ++i) {
                        uint2 dw;
                        dw.x = (unsigned)f[0][b].u[i] | ((unsigned)f[1][b].u[i] << 16);
                        dw.y = (unsigned)f[2][b].u[i] | ((unsigned)f[3][b].u[i] << 16);
                        *(uint2*)&Vt[((dbb + b) * 8 + i) * PV + kcol] = dw;
                    }
                }
            }
            if (kt + 1 < nkt) PRE(kt + 1);   // in flight across barrier
            bar_lds();                  // staging visible

            // ---- two 32-key subtiles of this wave's 64 keys ----
            #pragma unroll
            for (int sub = 0; sub < 2; ++sub) {
                // S^T = K Q^T over 4 d-slices
                floatx16 S = {};
                const int key = w * 64 + sub * 32 + col;
                #pragma unroll
                for (int s = 0; s < 4; ++s) {
                    short8 ka = *(const short8*)
                        &Ks[key * PK + (((2 * s + hi) + swadd) & 7) * 8];
                    S = MFMA32(ka, qa[s], S);
                }

                // softmax + in-register P (r13-verified math)
                const bool diag = (kt == nkt - 1);
                const int kbase = kt * 128 + w * 64 + sub * 32;
                const int qabs  = q0 + col;
                unsigned bfr[2][4];
                #pragma unroll
                for (int h2 = 0; h2 < 2; ++h2) {
                    float pv[8];
                    #pragma unroll
                    for (int j = 0; j < 8; ++j) {
                        const int reg = h2 * 8 + j;
                        const int kl  = (reg & 3) + 8 * (reg >> 2) + 4 * hi;
                        float e = exp2f(S[reg]);
                        if (diag && (kbase + kl > qabs)) e = 0.0f;
                        pv[j] = e;
                        lacc += e;
                    }
                    unsigned a0 = cvt_pk_bf16(pv[0], pv[1]);
                    unsigned a1 = cvt_pk_bf16(pv[2], pv[3]);
                    unsigned a2 = cvt_pk_bf16(pv[4], pv[5]);
                    unsigned a3 = cvt_pk_bf16(pv[6], pv[7]);
                    asm volatile("v_permlane32_swap_b32 %0, %1" : "+v"(a0), "+v"(a2));
                    asm volatile("v_permlane32_swap_b32 %0, %1" : "+v"(a1), "+v"(a3));
                    bfr[h2][0] = a0; bfr[h2][1] = a1; bfr[h2][2] = a2; bfr[h2][3] = a3;
                }

                // PV: O^T += V^T P^T over this subtile's 32 keys
                #pragma unroll
                for (int h2 = 0; h2 < 2; ++h2) {
                    union { unsigned u[4]; short8 v; } pb;
                    pb.u[0] = bfr[h2][0]; pb.u[1] = bfr[h2][1];
                    pb.u[2] = bfr[h2][2]; pb.u[3] = bfr[h2][3];
                    const int kbv = ((8 * w + 4 * sub + 2 * h2 + hi) + swadd) & 15;
                    #pragma unroll
                    for (int dt = 0; dt < 2; ++dt) {
                        short8 va = *(const short8*)
                            &Vt[(dt * 32 + col) * PV + kbv * 8];
                        O[dt] = MFMA32(va, pb.v, O[dt]);
                    }
                }
            }
        }

        // ---- merge the two key-half waves ----
        lacc += __shfl_xor(lacc, 32);   // hi halves share q

        bar_lds();                      // all Ks/Vt reads done; scratch free
        if (w == 1) {
            #pragma unroll
            for (int dt = 0; dt < 2; ++dt)
                #pragma unroll
                for (int reg = 0; reg < 16; ++reg) {
                    const int dl = (reg & 3) + 8 * (reg >> 2) + 4 * hi;
                    Om[(dt * 32 + dl) * 33 + col] = O[dt][reg];
                }
            if (hi == 0) Lg[col] = lacc;
        }
        bar_lds();
        if (w == 0) {
            const float linv = 1.0f / (lacc + Lg[col]);
            #pragma unroll
            for (int dt = 0; dt < 2; ++dt)
                #pragma unroll
                for (int reg = 0; reg < 16; ++reg) {
                    const int dl = (reg & 3) + 8 * (reg >> 2) + 4 * hi;
                    const int d  = dt * 32 + dl;
                    const float v = O[dt][reg] + Om[d * 33 + col];
                    out[((size_t)bh * 64 + d) * NSEQ + q0 + col] = v * linv;
                }
        }
    }
#undef PRE
}

extern "C" void kernel_launch(void* const* d_in, const int* in_sizes, int n_in,
                              void* d_out, int out_size, void* d_ws, size_t ws_size,
                              hipStream_t stream)
{
    (void)in_sizes; (void)n_in; (void)out_size; (void)ws_size;
    const float* x  = (const float*)d_in[0];
    const float* Wq = (const float*)d_in[1];
    float* out = (float*)d_out;

    ushort* hb = (ushort*)d_ws;                 // 6.29 MB (ws is 256 MiB)

    qkv_mfma<<<dim3(64, 12), dim3(256), 0, stream>>>(x, Wq, hb);
    attn_mfma<<<dim3(32, 24), dim3(128), 0, stream>>>(hb, out);
}